// Round 1
// baseline (334.433 us; speedup 1.0000x reference)
//
#include <hip/hip_runtime.h>

#define MM 24
#define ROW_LEN (MM + 1)                 // 25 floats per row
#define RPB 64                           // ONE WAVE per block: barriers are wave-internal
                                         // (near-free), so every wave runs its own
                                         // load->compute->store pipeline independently.
#define FPB (RPB * ROW_LEN)              // 1600 floats of LDS per block (6.4 KB)
#define V4PB (FPB / 4)                   // 400 float4 per block
#define NIT ((V4PB + RPB - 1) / RPB)     // 7 staging iterations per thread

__global__ __launch_bounds__(RPB)
void lpc_stab_kernel(const float* __restrict__ a, float* __restrict__ out, int B) {
    __shared__ float lds[FPB];

    const long long total4 = ((long long)B * ROW_LEN) >> 2;   // B*25 divisible by 4
    const long long base4  = (long long)blockIdx.x * V4PB;
    const float4* a4 = (const float4*)a;
    float4*       o4 = (float4*)out;
    float4*       l4 = (float4*)lds;

    const bool interior = (base4 + V4PB) <= total4;

    // ---- coalesced global -> LDS (float4) ----
    if (interior) {
        #pragma unroll
        for (int it = 0; it < NIT; ++it) {
            int li = it * RPB + threadIdx.x;
            if (li < V4PB) l4[li] = a4[base4 + li];
        }
    } else {
        #pragma unroll
        for (int it = 0; it < NIT; ++it) {
            int li = it * RPB + threadIdx.x;
            if (li < V4PB && base4 + li < total4) l4[li] = a4[base4 + li];
        }
    }
    __syncthreads();   // single-wave workgroup: compiles to lgkmcnt wait, no real barrier

    const int row = blockIdx.x * RPB + threadIdx.x;
    if (row < B) {
        float* p = lds + threadIdx.x * ROW_LEN;   // stride 25: conflict-free (gcd(25,32)=1)
        float K = p[0];
        float c[MM], k[MM];
        #pragma unroll
        for (int j = 0; j < MM; ++j) c[j] = p[j + 1];

        // ---- step-down (LPC -> reflection coefficients) ----
        // clip is folded into extraction: the recursion itself must use UNCLIPPED km
        // (reference clips only after the full step-down), but the k[] that feeds
        // step-up is the clipped value.
        #pragma unroll
        for (int m = MM; m >= 1; --m) {
            float km = c[m - 1];
            k[m - 1] = fminf(fmaxf(km, -1.0f), 1.0f);   // BOUND == 1.0f in fp32
            if (m >= 2) {
                float inv = __builtin_amdgcn_rcpf(1.0f - km * km);
                #pragma unroll
                for (int i = 0; i < (m - 1) / 2; ++i) {
                    float x = c[i], y = c[m - 2 - i];
                    c[i]         = (x - km * y) * inv;
                    c[m - 2 - i] = (y - km * x) * inv;
                }
                if ((m - 1) & 1) {                 // middle element pairs with itself
                    int i = (m - 1) / 2;
                    float x = c[i];
                    c[i] = (x - km * x) * inv;
                }
            }
        }

        // ---- step-up (reflection -> LPC), rebuild into c ----
        #pragma unroll
        for (int m = 1; m <= MM; ++m) {
            float km = k[m - 1];
            #pragma unroll
            for (int i = 0; i < (m - 1) / 2; ++i) {
                float x = c[i], y = c[m - 2 - i];
                c[i]         = x + km * y;
                c[m - 2 - i] = y + km * x;
            }
            if ((m >= 2) && ((m - 1) & 1)) {
                int i = (m - 1) / 2;
                c[i] = c[i] + km * c[i];
            }
            c[m - 1] = km;
        }

        // write result back into this thread's own LDS row (no cross-thread hazard)
        p[0] = K;
        #pragma unroll
        for (int j = 0; j < MM; ++j) p[j + 1] = c[j];
    }
    __syncthreads();

    // ---- coalesced LDS -> global (float4) ----
    if (interior) {
        #pragma unroll
        for (int it = 0; it < NIT; ++it) {
            int li = it * RPB + threadIdx.x;
            if (li < V4PB) o4[base4 + li] = l4[li];
        }
    } else {
        #pragma unroll
        for (int it = 0; it < NIT; ++it) {
            int li = it * RPB + threadIdx.x;
            if (li < V4PB && base4 + li < total4) o4[base4 + li] = l4[li];
        }
    }
}

extern "C" void kernel_launch(void* const* d_in, const int* in_sizes, int n_in,
                              void* d_out, int out_size, void* d_ws, size_t ws_size,
                              hipStream_t stream) {
    const float* a = (const float*)d_in[0];
    float* out = (float*)d_out;
    int B = in_sizes[0] / ROW_LEN;
    int blocks = (B + RPB - 1) / RPB;
    lpc_stab_kernel<<<blocks, RPB, 0, stream>>>(a, out, B);
}

// Round 2
// 332.382 us; speedup vs baseline: 1.0062x; 1.0062x over previous
//
#include <hip/hip_runtime.h>

#define MM 24
#define ROW_LEN 25
#define RPB 64                          // ONE wave per block
#define TILE_F (RPB * ROW_LEN)          // 1600 floats = 6400 B per tile
#define MAX_BLOCKS (256 * 12)           // 2 x 6.4 KB LDS/block -> 12 blocks/CU resident

// ---- async global -> LDS (no VGPR round-trip); size must be literal ----
__device__ __forceinline__ void gl_lds16(const float* g, float* l) {
    __builtin_amdgcn_global_load_lds((const __attribute__((address_space(1))) void*)g,
                                     (__attribute__((address_space(3))) void*)l,
                                     16, 0, 0);
}
__device__ __forceinline__ void gl_lds4(const float* g, float* l) {
    __builtin_amdgcn_global_load_lds((const __attribute__((address_space(1))) void*)g,
                                     (__attribute__((address_space(3))) void*)l,
                                     4, 0, 0);
}

// counted vmcnt: "memory" clobber keeps all memory ops (ds/global) ordered vs the wait
#define WAIT_VM(N) asm volatile("s_waitcnt vmcnt(" #N ")" ::: "memory")

// stage one 6400 B tile: 6 x (64 lanes x 16 B) + 1 x (64 lanes x 4 B) = exactly 6400 B
__device__ __forceinline__ void stage_tile(const float* __restrict__ a, float* buf,
                                           long long tile, int lane) {
    const float* g = a + tile * (long long)TILE_F;
    #pragma unroll
    for (int i = 0; i < 6; ++i)
        gl_lds16(g + i * 256 + lane * 4, buf + i * 256);   // lds dst: uniform base + lane*16
    gl_lds4(g + 1536 + lane, buf + 1536);                  // lds dst: uniform base + lane*4
}

// LDS tile -> regs -> coalesced global store (7 VMEM stores)
__device__ __forceinline__ void store_tile(float* __restrict__ outp, const float* buf,
                                           long long tile, int lane) {
    float4 r[6];
    #pragma unroll
    for (int i = 0; i < 6; ++i)
        r[i] = *(const float4*)(buf + i * 256 + lane * 4); // linear b128, conflict-free
    float rt = buf[1536 + lane];
    float* g = outp + tile * (long long)TILE_F;
    #pragma unroll
    for (int i = 0; i < 6; ++i)
        *(float4*)(g + i * 256 + lane * 4) = r[i];
    g[1536 + lane] = rt;
}

// step-down -> clip -> step-up on one row in LDS (p stride 25: gcd(25,32)=1, conflict-free)
// p[0] (gain K) passes through untouched: never read, never written.
__device__ __forceinline__ void lpc_row(float* p) {
    float c[MM], k[MM];
    #pragma unroll
    for (int j = 0; j < MM; ++j) c[j] = p[j + 1];

    #pragma unroll
    for (int m = MM; m >= 1; --m) {
        float km = c[m - 1];
        k[m - 1] = fminf(fmaxf(km, -1.0f), 1.0f);          // BOUND == 1.0f in fp32
        if (m >= 2) {
            float inv = __builtin_amdgcn_rcpf(1.0f - km * km);
            #pragma unroll
            for (int i = 0; i < (m - 1) / 2; ++i) {
                float x = c[i], y = c[m - 2 - i];
                c[i]         = (x - km * y) * inv;
                c[m - 2 - i] = (y - km * x) * inv;
            }
            if ((m - 1) & 1) {
                int i = (m - 1) / 2;
                float x = c[i];
                c[i] = (x - km * x) * inv;
            }
        }
    }

    #pragma unroll
    for (int m = 1; m <= MM; ++m) {
        float km = k[m - 1];
        #pragma unroll
        for (int i = 0; i < (m - 1) / 2; ++i) {
            float x = c[i], y = c[m - 2 - i];
            c[i]         = x + km * y;
            c[m - 2 - i] = y + km * x;
        }
        if ((m >= 2) && ((m - 1) & 1)) {
            int i = (m - 1) / 2;
            c[i] = c[i] + km * c[i];
        }
        c[m - 1] = km;
    }

    #pragma unroll
    for (int j = 0; j < MM; ++j) p[j + 1] = c[j];
}

__global__ __launch_bounds__(RPB, 3)
void lpc_stab_kernel(const float* __restrict__ a, float* __restrict__ out,
                     long long ntiles, int rem) {
    __shared__ float bufA[TILE_F];
    __shared__ float bufB[TILE_F];
    const int lane = threadIdx.x;
    const long long gstride = gridDim.x;
    long long t = blockIdx.x;

    if (t < ntiles) {
        // ---- prologue: 1-deep prefetch ----
        stage_tile(a, bufA, t, lane);                      // L(t0): 7 vmem
        float* cur = bufA;
        float* nxt = bufB;
        long long t1 = t + gstride;
        if (t1 < ntiles) {
            stage_tile(a, bufB, t1, lane);                 // L(t1): 7 vmem
            WAIT_VM(7);                                    // all but newest 7 done -> L(t0) done
        } else {
            WAIT_VM(0);
        }
        lpc_row(cur + lane * ROW_LEN);
        __syncthreads();                                   // row ds_writes visible to b128 reads
        store_tile(out, cur, t, lane);                     // S(t0): 7 vmem
        t = t1;
        { float* tmp = cur; cur = nxt; nxt = tmp; }

        // ---- steady state: [L(t) | S(t-1) | L(t+1)] outstanding, never drain to 0 ----
        while (t < ntiles) {
            const long long tn = t + gstride;
            if (tn < ntiles) {
                stage_tile(a, nxt, tn, lane);              // issue next-tile loads FIRST
                WAIT_VM(14);                               // leaves S(t-1)+L(t+1); L(t) done
            } else {
                WAIT_VM(7);                                // leaves S(t-1); L(t) done
            }
            lpc_row(cur + lane * ROW_LEN);
            __syncthreads();
            store_tile(out, cur, t, lane);
            t = tn;
            float* tmp = cur; cur = nxt; nxt = tmp;
        }
    }

    // ---- tail rows (B % 64): tiny, scalar path on block 0 ----
    if (rem && blockIdx.x == 0 && lane < rem) {
        const long long r0 = ntiles * RPB + lane;
        const float* gi = a + r0 * ROW_LEN;
        float* p = bufA + lane * ROW_LEN;                  // pipeline done; bufA free
        #pragma unroll
        for (int j = 0; j < ROW_LEN; ++j) p[j] = gi[j];
        lpc_row(p);
        float* go = out + r0 * ROW_LEN;
        #pragma unroll
        for (int j = 0; j < ROW_LEN; ++j) go[j] = p[j];
    }
}

extern "C" void kernel_launch(void* const* d_in, const int* in_sizes, int n_in,
                              void* d_out, int out_size, void* d_ws, size_t ws_size,
                              hipStream_t stream) {
    const float* a = (const float*)d_in[0];
    float* out = (float*)d_out;
    long long B = (long long)in_sizes[0] / ROW_LEN;
    long long ntiles = B / RPB;
    int rem = (int)(B % RPB);
    long long want = ntiles > 0 ? ntiles : 1;
    int blocks = (int)(want < MAX_BLOCKS ? want : MAX_BLOCKS);
    lpc_stab_kernel<<<blocks, RPB, 0, stream>>>(a, out, ntiles, rem);
}